// Round 6
// baseline (241.339 us; speedup 1.0000x reference)
//
#include <hip/hip_runtime.h>
#include <hip/hip_bf16.h>

#define NB 32
#define NT 1024
#define ND 256
#define DT 8          // d-columns per transform block
#define ETA 0.1f
#define INVS 0.70710678118654752440f

typedef short bf16x8 __attribute__((ext_vector_type(8)));
typedef float f32x4  __attribute__((ext_vector_type(4)));

__device__ inline unsigned short f2bf(float f){
  __hip_bfloat16 h = __float2bfloat16(f);
  return *reinterpret_cast<unsigned short*>(&h);
}
__device__ inline float bf2f(unsigned short u){
  return __uint_as_float(((unsigned int)u) << 16);
}

constexpr int ilog2c(int n){ int l = 0; while (n >>= 1) ++l; return l; }

// ================= transposed-LDS Haar butterflies =================
// LDS layout: 8 planes (one per d-column), each plane = 1024 contiguous floats.
// Butterfly reads/writes walk consecutive t within a plane -> bank = t%32, <=2-way.

// IDWT fused 2 levels: a[0..N) + d[N..2N) + dd[2N..4N) -> interleaved a'[0..4N)
template<int N>
__device__ inline void idwt2T(float* lds, int tid){
  constexpr int LG = ilog2c(N);
  constexpr int ITEMS = DT * N;
  if constexpr (ITEMS >= 256){
    constexpr int PER = ITEMS / 256;
    float v0[PER], v1[PER], v2[PER], v3[PER];
#pragma unroll
    for (int r = 0; r < PER; ++r){
      int idx = tid + r*256; int dc = idx >> LG; int k = idx & (N-1);
      int base = dc << 10;
      float a  = lds[base + k];
      float dv = lds[base + N + k];
      float d0 = lds[base + 2*N + 2*k];
      float d1 = lds[base + 2*N + 2*k + 1];
      float e = (a + dv) * INVS, o = (a - dv) * INVS;
      v0[r] = (e + d0) * INVS; v1[r] = (e - d0) * INVS;
      v2[r] = (o + d1) * INVS; v3[r] = (o - d1) * INVS;
    }
    __syncthreads();
#pragma unroll
    for (int r = 0; r < PER; ++r){
      int idx = tid + r*256; int dc = idx >> LG; int k = idx & (N-1);
      int base = dc << 10;
      lds[base + 4*k + 0] = v0[r];
      lds[base + 4*k + 1] = v1[r];
      lds[base + 4*k + 2] = v2[r];
      lds[base + 4*k + 3] = v3[r];
    }
    __syncthreads();
  } else {
    float v0 = 0.f, v1 = 0.f, v2 = 0.f, v3 = 0.f;
    int dc = tid >> LG, k = tid & (N-1);
    int base = dc << 10;
    bool act = tid < ITEMS;
    if (act){
      float a  = lds[base + k];
      float dv = lds[base + N + k];
      float d0 = lds[base + 2*N + 2*k];
      float d1 = lds[base + 2*N + 2*k + 1];
      float e = (a + dv) * INVS, o = (a - dv) * INVS;
      v0 = (e + d0) * INVS; v1 = (e - d0) * INVS;
      v2 = (o + d1) * INVS; v3 = (o - d1) * INVS;
    }
    __syncthreads();
    if (act){
      lds[base + 4*k + 0] = v0;
      lds[base + 4*k + 1] = v1;
      lds[base + 4*k + 2] = v2;
      lds[base + 4*k + 3] = v3;
    }
    __syncthreads();
  }
}

__device__ inline void idwt_all(float* lds, int tid){
  idwt2T<1>(lds, tid);  idwt2T<4>(lds, tid);   idwt2T<16>(lds, tid);
  idwt2T<64>(lds, tid); idwt2T<256>(lds, tid);
}

// DWT fused 2 levels: interleaved x[0..4N) -> a[0..N) + d2[N..2N) + d1[2N..4N)
template<int N>
__device__ inline void dwt2T(float* lds, int tid){
  constexpr int LG = ilog2c(N);
  constexpr int ITEMS = DT * N;
  if constexpr (ITEMS >= 256){
    constexpr int PER = ITEMS / 256;
    float va[PER], vd2[PER], vd1a[PER], vd1b[PER];
#pragma unroll
    for (int r = 0; r < PER; ++r){
      int idx = tid + r*256; int dc = idx >> LG; int k = idx & (N-1);
      int base = dc << 10;
      float x0 = lds[base + 4*k + 0];
      float x1 = lds[base + 4*k + 1];
      float x2 = lds[base + 4*k + 2];
      float x3 = lds[base + 4*k + 3];
      float a0 = (x0 + x1) * INVS, a1 = (x2 + x3) * INVS;
      vd1a[r] = (x0 - x1) * INVS; vd1b[r] = (x2 - x3) * INVS;
      va[r]   = (a0 + a1) * INVS; vd2[r]  = (a0 - a1) * INVS;
    }
    __syncthreads();
#pragma unroll
    for (int r = 0; r < PER; ++r){
      int idx = tid + r*256; int dc = idx >> LG; int k = idx & (N-1);
      int base = dc << 10;
      lds[base + k]             = va[r];
      lds[base + N + k]         = vd2[r];
      lds[base + 2*N + 2*k]     = vd1a[r];
      lds[base + 2*N + 2*k + 1] = vd1b[r];
    }
    __syncthreads();
  } else {
    float va = 0.f, vd2 = 0.f, vd1a = 0.f, vd1b = 0.f;
    int dc = tid >> LG, k = tid & (N-1);
    int base = dc << 10;
    bool act = tid < ITEMS;
    if (act){
      float x0 = lds[base + 4*k + 0];
      float x1 = lds[base + 4*k + 1];
      float x2 = lds[base + 4*k + 2];
      float x3 = lds[base + 4*k + 3];
      float a0 = (x0 + x1) * INVS, a1 = (x2 + x3) * INVS;
      vd1a = (x0 - x1) * INVS; vd1b = (x2 - x3) * INVS;
      va   = (a0 + a1) * INVS; vd2  = (a0 - a1) * INVS;
    }
    __syncthreads();
    if (act){
      lds[base + k]             = va;
      lds[base + N + k]         = vd2;
      lds[base + 2*N + 2*k]     = vd1a;
      lds[base + 2*N + 2*k + 1] = vd1b;
    }
    __syncthreads();
  }
}

__device__ inline void dwt_all(float* lds, int tid){
  dwt2T<256>(lds, tid); dwt2T<64>(lds, tid); dwt2T<16>(lds, tid);
  dwt2T<4>(lds, tid);   dwt2T<1>(lds, tid);
}

// ---------------- kernel A: c = w*rho (store); S = bf16(IDWT(c)) ----------------
__global__ __launch_bounds__(256, 5) void k_idwt_first(const float* __restrict__ rho,
                                                       const float* __restrict__ w,
                                                       float* __restrict__ c,
                                                       unsigned short* __restrict__ S){
  __shared__ float lds[DT * 1024];
  int tid = threadIdx.x;
  int b = blockIdx.y;
  int d0 = blockIdx.x * DT;
  size_t base = ((size_t)b * NT) * ND;
#pragma unroll
  for (int r = 0; r < 8; ++r){
    int q = tid + r*256; int t = q >> 1, qq = q & 1;
    size_t g = base + (size_t)t*ND + d0 + qq*4;
    float4 rv = *(const float4*)(rho + g);
    float4 wv = *(const float4*)(w + (size_t)t*ND + d0 + qq*4);
    float4 cv; cv.x = rv.x*wv.x; cv.y = rv.y*wv.y; cv.z = rv.z*wv.z; cv.w = rv.w*wv.w;
    *(float4*)(c + g) = cv;
    lds[(qq*4 + 0)*1024 + t] = cv.x;
    lds[(qq*4 + 1)*1024 + t] = cv.y;
    lds[(qq*4 + 2)*1024 + t] = cv.z;
    lds[(qq*4 + 3)*1024 + t] = cv.w;
  }
  __syncthreads();
  idwt_all(lds, tid);
#pragma unroll
  for (int r = 0; r < 8; ++r){
    int q = tid + r*256; int t = q >> 1, qq = q & 1;
    size_t g = base + (size_t)t*ND + d0 + qq*4;
    ushort4 o;
    o.x = f2bf(lds[(qq*4 + 0)*1024 + t]);
    o.y = f2bf(lds[(qq*4 + 1)*1024 + t]);
    o.z = f2bf(lds[(qq*4 + 2)*1024 + t]);
    o.w = f2bf(lds[(qq*4 + 3)*1024 + t]);
    *(ushort4*)(S + g) = o;
  }
}

// ---------------- kernel C: DWT(Y) -> blend c (store) -> IDWT -> S ----------------
__global__ __launch_bounds__(256, 5) void k_dwt_update_idwt(const unsigned short* __restrict__ Y,
                                                            float* __restrict__ c,
                                                            unsigned short* __restrict__ S){
  __shared__ float lds[DT * 1024];
  int tid = threadIdx.x;
  int b = blockIdx.y;
  int d0 = blockIdx.x * DT;
  size_t base = ((size_t)b * NT) * ND;
#pragma unroll
  for (int r = 0; r < 8; ++r){
    int q = tid + r*256; int t = q >> 1, qq = q & 1;
    size_t g = base + (size_t)t*ND + d0 + qq*4;
    ushort4 yv = *(const ushort4*)(Y + g);
    lds[(qq*4 + 0)*1024 + t] = bf2f(yv.x);
    lds[(qq*4 + 1)*1024 + t] = bf2f(yv.y);
    lds[(qq*4 + 2)*1024 + t] = bf2f(yv.z);
    lds[(qq*4 + 3)*1024 + t] = bf2f(yv.w);
  }
  __syncthreads();
  dwt_all(lds, tid);
#pragma unroll
  for (int r = 0; r < 8; ++r){
    int q = tid + r*256; int t = q >> 1, qq = q & 1;
    size_t g = base + (size_t)t*ND + d0 + qq*4;
    float4 cv = *(const float4*)(c + g);
    float4 x;
    x.x = lds[(qq*4 + 0)*1024 + t];
    x.y = lds[(qq*4 + 1)*1024 + t];
    x.z = lds[(qq*4 + 2)*1024 + t];
    x.w = lds[(qq*4 + 3)*1024 + t];
    float4 nc;
    nc.x = cv.x - ETA*(cv.x - x.x);
    nc.y = cv.y - ETA*(cv.y - x.y);
    nc.z = cv.z - ETA*(cv.z - x.z);
    nc.w = cv.w - ETA*(cv.w - x.w);
    *(float4*)(c + g) = nc;
    lds[(qq*4 + 0)*1024 + t] = nc.x;
    lds[(qq*4 + 1)*1024 + t] = nc.y;
    lds[(qq*4 + 2)*1024 + t] = nc.z;
    lds[(qq*4 + 3)*1024 + t] = nc.w;
  }
  __syncthreads();
  idwt_all(lds, tid);
#pragma unroll
  for (int r = 0; r < 8; ++r){
    int q = tid + r*256; int t = q >> 1, qq = q & 1;
    size_t g = base + (size_t)t*ND + d0 + qq*4;
    ushort4 o;
    o.x = f2bf(lds[(qq*4 + 0)*1024 + t]);
    o.y = f2bf(lds[(qq*4 + 1)*1024 + t]);
    o.z = f2bf(lds[(qq*4 + 2)*1024 + t]);
    o.w = f2bf(lds[(qq*4 + 3)*1024 + t]);
    *(ushort4*)(S + g) = o;
  }
}

// ---------------- kernel E: DWT(Y) -> out = blend(c,.)/w ----------------
__global__ __launch_bounds__(256, 5) void k_dwt_final(const unsigned short* __restrict__ Y,
                                                      float* __restrict__ c,
                                                      const float* __restrict__ w){
  __shared__ float lds[DT * 1024];
  int tid = threadIdx.x;
  int b = blockIdx.y;
  int d0 = blockIdx.x * DT;
  size_t base = ((size_t)b * NT) * ND;
#pragma unroll
  for (int r = 0; r < 8; ++r){
    int q = tid + r*256; int t = q >> 1, qq = q & 1;
    size_t g = base + (size_t)t*ND + d0 + qq*4;
    ushort4 yv = *(const ushort4*)(Y + g);
    lds[(qq*4 + 0)*1024 + t] = bf2f(yv.x);
    lds[(qq*4 + 1)*1024 + t] = bf2f(yv.y);
    lds[(qq*4 + 2)*1024 + t] = bf2f(yv.z);
    lds[(qq*4 + 3)*1024 + t] = bf2f(yv.w);
  }
  __syncthreads();
  dwt_all(lds, tid);
#pragma unroll
  for (int r = 0; r < 8; ++r){
    int q = tid + r*256; int t = q >> 1, qq = q & 1;
    size_t g = base + (size_t)t*ND + d0 + qq*4;
    float4 cv = *(const float4*)(c + g);
    float4 x;
    x.x = lds[(qq*4 + 0)*1024 + t];
    x.y = lds[(qq*4 + 1)*1024 + t];
    x.z = lds[(qq*4 + 2)*1024 + t];
    x.w = lds[(qq*4 + 3)*1024 + t];
    float4 wv = *(const float4*)(w + (size_t)t*ND + d0 + qq*4);
    float4 ov;
    ov.x = (cv.x - ETA*(cv.x - x.x)) / wv.x;
    ov.y = (cv.y - ETA*(cv.y - x.y)) / wv.y;
    ov.z = (cv.z - ETA*(cv.z - x.z)) / wv.z;
    ov.w = (cv.w - ETA*(cv.w - x.w)) / wv.w;
    *(float4*)(c + g) = ov;
  }
}

// ---------------- per-band GEMM, register-held B panel, TM=2 tiles/block ----------------
__global__ __launch_bounds__(256, 2) void k_band_gemm(const unsigned short* __restrict__ S,
                                                      const unsigned short* __restrict__ Wt,
                                                      const float* __restrict__ bias,
                                                      unsigned short* __restrict__ Y){
  int bx = blockIdx.x;  // 0..591
  int wv = threadIdx.x >> 6, lane = threadIdx.x & 63;
  int row = lane & 15, kg = lane >> 4;
  int band, jbase; bool masked = false;
  if      (bx <  16){ band =  6; jbase = bx*2; }
  else if (bx <  48){ band =  7; jbase = (bx-16)*2; }
  else if (bx < 112){ band =  8; jbase = (bx-48)*2; }
  else if (bx < 240){ band =  9; jbase = (bx-112)*2; }
  else if (bx < 496){ band = 10; jbase = (bx-240)*2; }
  else { masked = true; int mb = bx-496; band = mb>>4; jbase = (mb&15)*2; }

  int n0 = wv * 64;
  const unsigned short* Wb = Wt + (size_t)band * 65536;

  bf16x8 breg[8][4];
#pragma unroll
  for (int kk = 0; kk < 8; ++kk)
#pragma unroll
    for (int ni = 0; ni < 4; ++ni)
      breg[kk][ni] = *(const bf16x8*)(Wb + (size_t)(n0 + 16*ni + row)*256 + kk*32 + kg*8);

  float bv[4];
#pragma unroll
  for (int ni = 0; ni < 4; ++ni) bv[ni] = bias[band*256 + n0 + 16*ni + row];

  int lo = 0, hi = 0;
  if (masked){
    lo = (band == 0) ? 0 : (1 << (band - 1));
    hi = (band == 0) ? 1 : (1 << band);
  }
  int shift = masked ? 0 : (band - 6);
  int tstart = masked ? 0 : (32 << shift);

  for (int m = 0; m < 2; ++m){
    int j = jbase + m;
    int bb, t0;
    if (masked){ bb = j; t0 = 0; }
    else { bb = j >> shift; t0 = tstart + (j & ((1 << shift) - 1)) * 32; }

    f32x4 acc[2][4];
#pragma unroll
    for (int mi = 0; mi < 2; ++mi)
#pragma unroll
      for (int ni = 0; ni < 4; ++ni) acc[mi][ni] = (f32x4){0.f, 0.f, 0.f, 0.f};

    size_t arow0 = ((size_t)bb * NT + t0 + row) * ND;
#pragma unroll
    for (int kk = 0; kk < 8; ++kk){
      int k = kk*32 + kg*8;
      bf16x8 a0 = *(const bf16x8*)(S + arow0 + k);
      bf16x8 a1 = *(const bf16x8*)(S + arow0 + 16*ND + k);
#pragma unroll
      for (int ni = 0; ni < 4; ++ni){
        acc[0][ni] = __builtin_amdgcn_mfma_f32_16x16x32_bf16(a0, breg[kk][ni], acc[0][ni], 0, 0, 0);
        acc[1][ni] = __builtin_amdgcn_mfma_f32_16x16x32_bf16(a1, breg[kk][ni], acc[1][ni], 0, 0, 0);
      }
    }
#pragma unroll
    for (int ni = 0; ni < 4; ++ni){
#pragma unroll
      for (int mi = 0; mi < 2; ++mi){
#pragma unroll
        for (int jj = 0; jj < 4; ++jj){
          int t = t0 + 16*mi + kg*4 + jj;   // C/D: row=(lane>>4)*4+reg, col=lane&15
          if (!masked || (t >= lo && t < hi)){
            Y[((size_t)bb*NT + t)*ND + n0 + 16*ni + row] = f2bf(acc[mi][ni][jj] + bv[ni]);
          }
        }
      }
    }
  }
}

// ---------------- Wt[band][e][d] = bf16(W[band][d][e]) ----------------
__global__ __launch_bounds__(256) void k_wprep(const float* __restrict__ W,
                                               unsigned short* __restrict__ Wt){
  __shared__ float tbuf[32][33];
  int band = blockIdx.y;
  int tile = blockIdx.x;             // 0..63 -> 8x8 grid of 32x32 tiles
  int td0 = (tile >> 3) * 32, te0 = (tile & 7) * 32;
  int tx = threadIdx.x & 31, ty = threadIdx.x >> 5;
#pragma unroll
  for (int i = 0; i < 4; ++i){
    tbuf[ty*4 + i][tx] = W[(size_t)band*65536 + (size_t)(td0 + ty*4 + i)*256 + te0 + tx];
  }
  __syncthreads();
#pragma unroll
  for (int i = 0; i < 4; ++i){
    Wt[(size_t)band*65536 + (size_t)(te0 + ty*4 + i)*256 + td0 + tx] = f2bf(tbuf[tx][ty*4 + i]);
  }
}

extern "C" void kernel_launch(void* const* d_in, const int* in_sizes, int n_in,
                              void* d_out, int out_size, void* d_ws, size_t ws_size,
                              hipStream_t stream){
  const float* rho  = (const float*)d_in[0];
  const float* w    = (const float*)d_in[1];
  const float* W    = (const float*)d_in[2];
  const float* bias = (const float*)d_in[3];

  float* c = (float*)d_out;                                   // coeff state lives in d_out
  unsigned short* S  = (unsigned short*)d_ws;                 // 16 MB bf16 signal
  unsigned short* Y  = S + (size_t)NB * NT * ND;              // 16 MB bf16 predicted signal
  unsigned short* Wt = Y + (size_t)NB * NT * ND;              // 1.4 MB bf16 transposed weights

  k_wprep<<<dim3(64, 11), 256, 0, stream>>>(W, Wt);
  k_idwt_first<<<dim3(ND/DT, NB), 256, 0, stream>>>(rho, w, c, S);
  k_band_gemm<<<592, 256, 0, stream>>>(S, Wt, bias, Y);
  k_dwt_update_idwt<<<dim3(ND/DT, NB), 256, 0, stream>>>(Y, c, S);
  k_band_gemm<<<592, 256, 0, stream>>>(S, Wt, bias, Y);
  k_dwt_final<<<dim3(ND/DT, NB), 256, 0, stream>>>(Y, c, w);
}

// Round 7
// 154.791 us; speedup vs baseline: 1.5591x; 1.5591x over previous
//
#include <hip/hip_runtime.h>
#include <hip/hip_bf16.h>

// Problem constants
#define NB 32
#define NT 1024
#define ND 256
#define DT 16     // d-columns per transform block
#define LDP 16    // LDS row pitch (floats)
#define TTH 512   // threads per transform block
#define ETA 0.1f
#define INVS 0.70710678118654752440f

typedef short bf16x8 __attribute__((ext_vector_type(8)));
typedef float f32x4  __attribute__((ext_vector_type(4)));

__device__ inline unsigned short f2bf(float f){
  __hip_bfloat16 h = __float2bfloat16(f);
  return *reinterpret_cast<unsigned short*>(&h);
}
__device__ inline float bf2f(unsigned short u){
  return __uint_as_float(((unsigned int)u) << 16);
}

// ---------------- fused 2-level Haar butterflies (LDS tile: NT x DT, pitch LDP) ----------------
// IDWT fused pass: a[0..N) + d[N..2N) + dd[2N..4N) -> interleaved a'[0..4N)
// item = (k, dc): k in [0,N), dc in [0,16)
template<int N>
__device__ inline void idwt2_stage(float* lds, int tid){
  constexpr int ITEMS = N * DT;
  if constexpr (ITEMS >= TTH) {
    constexpr int PER = ITEMS / TTH;
    float v0[PER], v1[PER], v2[PER], v3[PER];
#pragma unroll
    for (int r = 0; r < PER; ++r){
      int idx = tid + r*TTH; int k = idx >> 4, dc = idx & 15;
      float a  = lds[k*LDP + dc];
      float d  = lds[(N + k)*LDP + dc];
      float d0 = lds[(2*N + 2*k)*LDP + dc];
      float d1 = lds[(2*N + 2*k + 1)*LDP + dc];
      float e = (a + d) * INVS, o = (a - d) * INVS;
      v0[r] = (e + d0) * INVS; v1[r] = (e - d0) * INVS;
      v2[r] = (o + d1) * INVS; v3[r] = (o - d1) * INVS;
    }
    __syncthreads();
#pragma unroll
    for (int r = 0; r < PER; ++r){
      int idx = tid + r*TTH; int k = idx >> 4, dc = idx & 15;
      lds[(4*k + 0)*LDP + dc] = v0[r];
      lds[(4*k + 1)*LDP + dc] = v1[r];
      lds[(4*k + 2)*LDP + dc] = v2[r];
      lds[(4*k + 3)*LDP + dc] = v3[r];
    }
    __syncthreads();
  } else {
    float v0 = 0.f, v1 = 0.f, v2 = 0.f, v3 = 0.f;
    int k = tid >> 4, dc = tid & 15;
    bool act = tid < ITEMS;
    if (act){
      float a  = lds[k*LDP + dc];
      float d  = lds[(N + k)*LDP + dc];
      float d0 = lds[(2*N + 2*k)*LDP + dc];
      float d1 = lds[(2*N + 2*k + 1)*LDP + dc];
      float e = (a + d) * INVS, o = (a - d) * INVS;
      v0 = (e + d0) * INVS; v1 = (e - d0) * INVS;
      v2 = (o + d1) * INVS; v3 = (o - d1) * INVS;
    }
    __syncthreads();
    if (act){
      lds[(4*k + 0)*LDP + dc] = v0;
      lds[(4*k + 1)*LDP + dc] = v1;
      lds[(4*k + 2)*LDP + dc] = v2;
      lds[(4*k + 3)*LDP + dc] = v3;
    }
    __syncthreads();
  }
}

__device__ inline void idwt_all(float* lds, int tid){
  idwt2_stage<1>(lds, tid);   idwt2_stage<4>(lds, tid);  idwt2_stage<16>(lds, tid);
  idwt2_stage<64>(lds, tid);  idwt2_stage<256>(lds, tid);
}

// DWT fused pass: interleaved x[0..4N) -> a[0..N) + d2[N..2N) + d1[2N..4N)
template<int N>
__device__ inline void dwt2_stage(float* lds, int tid){
  constexpr int ITEMS = N * DT;
  if constexpr (ITEMS >= TTH) {
    constexpr int PER = ITEMS / TTH;
    float va[PER], vd2[PER], vd1a[PER], vd1b[PER];
#pragma unroll
    for (int r = 0; r < PER; ++r){
      int idx = tid + r*TTH; int k = idx >> 4, dc = idx & 15;
      float x0 = lds[(4*k + 0)*LDP + dc];
      float x1 = lds[(4*k + 1)*LDP + dc];
      float x2 = lds[(4*k + 2)*LDP + dc];
      float x3 = lds[(4*k + 3)*LDP + dc];
      float a0 = (x0 + x1) * INVS, a1 = (x2 + x3) * INVS;
      vd1a[r] = (x0 - x1) * INVS; vd1b[r] = (x2 - x3) * INVS;
      va[r]  = (a0 + a1) * INVS;  vd2[r]  = (a0 - a1) * INVS;
    }
    __syncthreads();
#pragma unroll
    for (int r = 0; r < PER; ++r){
      int idx = tid + r*TTH; int k = idx >> 4, dc = idx & 15;
      lds[k*LDP + dc]                 = va[r];
      lds[(N + k)*LDP + dc]           = vd2[r];
      lds[(2*N + 2*k)*LDP + dc]       = vd1a[r];
      lds[(2*N + 2*k + 1)*LDP + dc]   = vd1b[r];
    }
    __syncthreads();
  } else {
    float va = 0.f, vd2 = 0.f, vd1a = 0.f, vd1b = 0.f;
    int k = tid >> 4, dc = tid & 15;
    bool act = tid < ITEMS;
    if (act){
      float x0 = lds[(4*k + 0)*LDP + dc];
      float x1 = lds[(4*k + 1)*LDP + dc];
      float x2 = lds[(4*k + 2)*LDP + dc];
      float x3 = lds[(4*k + 3)*LDP + dc];
      float a0 = (x0 + x1) * INVS, a1 = (x2 + x3) * INVS;
      vd1a = (x0 - x1) * INVS; vd1b = (x2 - x3) * INVS;
      va  = (a0 + a1) * INVS;  vd2  = (a0 - a1) * INVS;
    }
    __syncthreads();
    if (act){
      lds[k*LDP + dc]                 = va;
      lds[(N + k)*LDP + dc]           = vd2;
      lds[(2*N + 2*k)*LDP + dc]       = vd1a;
      lds[(2*N + 2*k + 1)*LDP + dc]   = vd1b;
    }
    __syncthreads();
  }
}

__device__ inline void dwt_all(float* lds, int tid){
  dwt2_stage<256>(lds, tid); dwt2_stage<64>(lds, tid); dwt2_stage<16>(lds, tid);
  dwt2_stage<4>(lds, tid);   dwt2_stage<1>(lds, tid);
}

// ---------------- kernel A: c = w*rho (store); S = bf16(IDWT(c)) ----------------
__global__ __launch_bounds__(TTH, 4) void k_idwt_first(const float* __restrict__ rho,
                                                       const float* __restrict__ w,
                                                       float* __restrict__ c,
                                                       unsigned short* __restrict__ S){
  __shared__ float lds[NT * LDP];
  int tid = threadIdx.x;
  int b = blockIdx.y;
  int d0 = blockIdx.x * DT;
  size_t base = ((size_t)b * NT) * ND;
#pragma unroll
  for (int r = 0; r < 8; ++r){
    int q = tid + r*TTH; int t = q >> 2, qq = q & 3;
    size_t g = base + (size_t)t*ND + d0 + qq*4;
    float4 rv = *(const float4*)(rho + g);
    float4 wv = *(const float4*)(w + (size_t)t*ND + d0 + qq*4);
    float4 cv; cv.x = rv.x*wv.x; cv.y = rv.y*wv.y; cv.z = rv.z*wv.z; cv.w = rv.w*wv.w;
    *(float4*)(c + g) = cv;
    *(float4*)(&lds[t*LDP + qq*4]) = cv;
  }
  __syncthreads();
  idwt_all(lds, tid);
#pragma unroll
  for (int r = 0; r < 8; ++r){
    int q = tid + r*TTH; int t = q >> 2, qq = q & 3;
    size_t g = base + (size_t)t*ND + d0 + qq*4;
    float4 v = *(float4*)(&lds[t*LDP + qq*4]);
    ushort4 o; o.x = f2bf(v.x); o.y = f2bf(v.y); o.z = f2bf(v.z); o.w = f2bf(v.w);
    *(ushort4*)(S + g) = o;
  }
}

// ---------------- kernel C: DWT(Y) -> blend c (store) -> IDWT -> S ----------------
__global__ __launch_bounds__(TTH, 4) void k_dwt_update_idwt(const unsigned short* __restrict__ Y,
                                                            float* __restrict__ c,
                                                            unsigned short* __restrict__ S){
  __shared__ float lds[NT * LDP];
  int tid = threadIdx.x;
  int b = blockIdx.y;
  int d0 = blockIdx.x * DT;
  size_t base = ((size_t)b * NT) * ND;
#pragma unroll
  for (int r = 0; r < 8; ++r){
    int q = tid + r*TTH; int t = q >> 2, qq = q & 3;
    size_t g = base + (size_t)t*ND + d0 + qq*4;
    ushort4 yv = *(const ushort4*)(Y + g);
    lds[t*LDP + qq*4 + 0] = bf2f(yv.x);
    lds[t*LDP + qq*4 + 1] = bf2f(yv.y);
    lds[t*LDP + qq*4 + 2] = bf2f(yv.z);
    lds[t*LDP + qq*4 + 3] = bf2f(yv.w);
  }
  __syncthreads();
  dwt_all(lds, tid);
#pragma unroll
  for (int r = 0; r < 8; ++r){
    int q = tid + r*TTH; int t = q >> 2, qq = q & 3;
    size_t g = base + (size_t)t*ND + d0 + qq*4;
    float4 cv = *(const float4*)(c + g);
    float4 x  = *(float4*)(&lds[t*LDP + qq*4]);
    float4 nc;
    nc.x = cv.x - ETA*(cv.x - x.x);
    nc.y = cv.y - ETA*(cv.y - x.y);
    nc.z = cv.z - ETA*(cv.z - x.z);
    nc.w = cv.w - ETA*(cv.w - x.w);
    *(float4*)(c + g) = nc;
    *(float4*)(&lds[t*LDP + qq*4]) = nc;
  }
  __syncthreads();
  idwt_all(lds, tid);
#pragma unroll
  for (int r = 0; r < 8; ++r){
    int q = tid + r*TTH; int t = q >> 2, qq = q & 3;
    size_t g = base + (size_t)t*ND + d0 + qq*4;
    float4 v = *(float4*)(&lds[t*LDP + qq*4]);
    ushort4 o; o.x = f2bf(v.x); o.y = f2bf(v.y); o.z = f2bf(v.z); o.w = f2bf(v.w);
    *(ushort4*)(S + g) = o;
  }
}

// ---------------- kernel E: DWT(Y) -> out = blend(c,.)/w ----------------
__global__ __launch_bounds__(TTH, 4) void k_dwt_final(const unsigned short* __restrict__ Y,
                                                      float* __restrict__ c,
                                                      const float* __restrict__ w){
  __shared__ float lds[NT * LDP];
  int tid = threadIdx.x;
  int b = blockIdx.y;
  int d0 = blockIdx.x * DT;
  size_t base = ((size_t)b * NT) * ND;
#pragma unroll
  for (int r = 0; r < 8; ++r){
    int q = tid + r*TTH; int t = q >> 2, qq = q & 3;
    size_t g = base + (size_t)t*ND + d0 + qq*4;
    ushort4 yv = *(const ushort4*)(Y + g);
    lds[t*LDP + qq*4 + 0] = bf2f(yv.x);
    lds[t*LDP + qq*4 + 1] = bf2f(yv.y);
    lds[t*LDP + qq*4 + 2] = bf2f(yv.z);
    lds[t*LDP + qq*4 + 3] = bf2f(yv.w);
  }
  __syncthreads();
  dwt_all(lds, tid);
#pragma unroll
  for (int r = 0; r < 8; ++r){
    int q = tid + r*TTH; int t = q >> 2, qq = q & 3;
    size_t g = base + (size_t)t*ND + d0 + qq*4;
    float4 cv = *(const float4*)(c + g);
    float4 x  = *(float4*)(&lds[t*LDP + qq*4]);
    float4 wv = *(const float4*)(w + (size_t)t*ND + d0 + qq*4);
    float4 ov;
    ov.x = (cv.x - ETA*(cv.x - x.x)) / wv.x;
    ov.y = (cv.y - ETA*(cv.y - x.y)) / wv.y;
    ov.z = (cv.z - ETA*(cv.z - x.z)) / wv.z;
    ov.w = (cv.w - ETA*(cv.w - x.w)) / wv.w;
    *(float4*)(c + g) = ov;
  }
}

// ---------------- per-band GEMM, register-held B panel, TM=2 tiles/block ----------------
__global__ __launch_bounds__(256, 2) void k_band_gemm(const unsigned short* __restrict__ S,
                                                      const unsigned short* __restrict__ Wt,
                                                      const float* __restrict__ bias,
                                                      unsigned short* __restrict__ Y){
  int bx = blockIdx.x;  // 0..591
  int wv = threadIdx.x >> 6, lane = threadIdx.x & 63;
  int row = lane & 15, kg = lane >> 4;
  int band, jbase; bool masked = false;
  if      (bx <  16){ band =  6; jbase = bx*2; }
  else if (bx <  48){ band =  7; jbase = (bx-16)*2; }
  else if (bx < 112){ band =  8; jbase = (bx-48)*2; }
  else if (bx < 240){ band =  9; jbase = (bx-112)*2; }
  else if (bx < 496){ band = 10; jbase = (bx-240)*2; }
  else { masked = true; int mb = bx-496; band = mb>>4; jbase = (mb&15)*2; }

  int n0 = wv * 64;
  const unsigned short* Wb = Wt + (size_t)band * 65536;

  bf16x8 breg[8][4];
#pragma unroll
  for (int kk = 0; kk < 8; ++kk)
#pragma unroll
    for (int ni = 0; ni < 4; ++ni)
      breg[kk][ni] = *(const bf16x8*)(Wb + (size_t)(n0 + 16*ni + row)*256 + kk*32 + kg*8);

  float bv[4];
#pragma unroll
  for (int ni = 0; ni < 4; ++ni) bv[ni] = bias[band*256 + n0 + 16*ni + row];

  int lo = 0, hi = 0;
  if (masked){
    lo = (band == 0) ? 0 : (1 << (band - 1));
    hi = (band == 0) ? 1 : (1 << band);
  }
  int shift = masked ? 0 : (band - 6);
  int tstart = masked ? 0 : (32 << shift);

  for (int m = 0; m < 2; ++m){
    int j = jbase + m;
    int bb, t0;
    if (masked){ bb = j; t0 = 0; }
    else { bb = j >> shift; t0 = tstart + (j & ((1 << shift) - 1)) * 32; }

    f32x4 acc[2][4];
#pragma unroll
    for (int mi = 0; mi < 2; ++mi)
#pragma unroll
      for (int ni = 0; ni < 4; ++ni) acc[mi][ni] = (f32x4){0.f, 0.f, 0.f, 0.f};

    size_t arow0 = ((size_t)bb * NT + t0 + row) * ND;
#pragma unroll
    for (int kk = 0; kk < 8; ++kk){
      int k = kk*32 + kg*8;
      bf16x8 a0 = *(const bf16x8*)(S + arow0 + k);
      bf16x8 a1 = *(const bf16x8*)(S + arow0 + 16*ND + k);
#pragma unroll
      for (int ni = 0; ni < 4; ++ni){
        acc[0][ni] = __builtin_amdgcn_mfma_f32_16x16x32_bf16(a0, breg[kk][ni], acc[0][ni], 0, 0, 0);
        acc[1][ni] = __builtin_amdgcn_mfma_f32_16x16x32_bf16(a1, breg[kk][ni], acc[1][ni], 0, 0, 0);
      }
    }
#pragma unroll
    for (int ni = 0; ni < 4; ++ni){
#pragma unroll
      for (int mi = 0; mi < 2; ++mi){
#pragma unroll
        for (int jj = 0; jj < 4; ++jj){
          int t = t0 + 16*mi + kg*4 + jj;   // C/D: row=(lane>>4)*4+reg, col=lane&15
          if (!masked || (t >= lo && t < hi)){
            Y[((size_t)bb*NT + t)*ND + n0 + 16*ni + row] = f2bf(acc[mi][ni][jj] + bv[ni]);
          }
        }
      }
    }
  }
}

// ---------------- Wt[band][e][d] = bf16(W[band][d][e]) ----------------
__global__ __launch_bounds__(256) void k_wprep(const float* __restrict__ W,
                                               unsigned short* __restrict__ Wt){
  __shared__ float tbuf[32][33];
  int band = blockIdx.y;
  int tile = blockIdx.x;             // 0..63 -> 8x8 grid of 32x32 tiles
  int td0 = (tile >> 3) * 32, te0 = (tile & 7) * 32;
  int tx = threadIdx.x & 31, ty = threadIdx.x >> 5;
#pragma unroll
  for (int i = 0; i < 4; ++i){
    tbuf[ty*4 + i][tx] = W[(size_t)band*65536 + (size_t)(td0 + ty*4 + i)*256 + te0 + tx];
  }
  __syncthreads();
#pragma unroll
  for (int i = 0; i < 4; ++i){
    Wt[(size_t)band*65536 + (size_t)(te0 + ty*4 + i)*256 + td0 + tx] = f2bf(tbuf[tx][ty*4 + i]);
  }
}

extern "C" void kernel_launch(void* const* d_in, const int* in_sizes, int n_in,
                              void* d_out, int out_size, void* d_ws, size_t ws_size,
                              hipStream_t stream){
  const float* rho  = (const float*)d_in[0];
  const float* w    = (const float*)d_in[1];
  const float* W    = (const float*)d_in[2];
  const float* bias = (const float*)d_in[3];

  float* c = (float*)d_out;                                   // coeff state lives in d_out
  unsigned short* S  = (unsigned short*)d_ws;                 // 16 MB bf16 signal
  unsigned short* Y  = S + (size_t)NB * NT * ND;              // 16 MB bf16 predicted signal
  unsigned short* Wt = Y + (size_t)NB * NT * ND;              // 1.4 MB bf16 transposed weights

  k_wprep<<<dim3(64, 11), 256, 0, stream>>>(W, Wt);
  k_idwt_first<<<dim3(ND/DT, NB), TTH, 0, stream>>>(rho, w, c, S);
  k_band_gemm<<<592, 256, 0, stream>>>(S, Wt, bias, Y);
  k_dwt_update_idwt<<<dim3(ND/DT, NB), TTH, 0, stream>>>(Y, c, S);
  k_band_gemm<<<592, 256, 0, stream>>>(S, Wt, bias, Y);
  k_dwt_final<<<dim3(ND/DT, NB), TTH, 0, stream>>>(Y, c, w);
}

// Round 8
// 150.782 us; speedup vs baseline: 1.6006x; 1.0266x over previous
//
#include <hip/hip_runtime.h>
#include <hip/hip_bf16.h>

// Problem constants
#define NB 32
#define NT 1024
#define ND 256
#define DT 16     // d-columns per transform block
#define LDP 16    // LDS row pitch (floats)
#define TTH 512   // threads per transform block
#define ETA 0.1f
#define INVS 0.70710678118654752440f

typedef short bf16x8 __attribute__((ext_vector_type(8)));
typedef float f32x4  __attribute__((ext_vector_type(4)));

__device__ inline unsigned short f2bf(float f){
  __hip_bfloat16 h = __float2bfloat16(f);
  return *reinterpret_cast<unsigned short*>(&h);
}
__device__ inline float bf2f(unsigned short u){
  return __uint_as_float(((unsigned int)u) << 16);
}

// ---------------- fused 2-level Haar butterflies (LDS tile: NT x DT, pitch LDP) ----------------
template<int N>
__device__ inline void idwt2_stage(float* lds, int tid){
  constexpr int ITEMS = N * DT;
  if constexpr (ITEMS >= TTH) {
    constexpr int PER = ITEMS / TTH;
    float v0[PER], v1[PER], v2[PER], v3[PER];
#pragma unroll
    for (int r = 0; r < PER; ++r){
      int idx = tid + r*TTH; int k = idx >> 4, dc = idx & 15;
      float a  = lds[k*LDP + dc];
      float d  = lds[(N + k)*LDP + dc];
      float d0 = lds[(2*N + 2*k)*LDP + dc];
      float d1 = lds[(2*N + 2*k + 1)*LDP + dc];
      float e = (a + d) * INVS, o = (a - d) * INVS;
      v0[r] = (e + d0) * INVS; v1[r] = (e - d0) * INVS;
      v2[r] = (o + d1) * INVS; v3[r] = (o - d1) * INVS;
    }
    __syncthreads();
#pragma unroll
    for (int r = 0; r < PER; ++r){
      int idx = tid + r*TTH; int k = idx >> 4, dc = idx & 15;
      lds[(4*k + 0)*LDP + dc] = v0[r];
      lds[(4*k + 1)*LDP + dc] = v1[r];
      lds[(4*k + 2)*LDP + dc] = v2[r];
      lds[(4*k + 3)*LDP + dc] = v3[r];
    }
    __syncthreads();
  } else {
    float v0 = 0.f, v1 = 0.f, v2 = 0.f, v3 = 0.f;
    int k = tid >> 4, dc = tid & 15;
    bool act = tid < ITEMS;
    if (act){
      float a  = lds[k*LDP + dc];
      float d  = lds[(N + k)*LDP + dc];
      float d0 = lds[(2*N + 2*k)*LDP + dc];
      float d1 = lds[(2*N + 2*k + 1)*LDP + dc];
      float e = (a + d) * INVS, o = (a - d) * INVS;
      v0 = (e + d0) * INVS; v1 = (e - d0) * INVS;
      v2 = (o + d1) * INVS; v3 = (o - d1) * INVS;
    }
    __syncthreads();
    if (act){
      lds[(4*k + 0)*LDP + dc] = v0;
      lds[(4*k + 1)*LDP + dc] = v1;
      lds[(4*k + 2)*LDP + dc] = v2;
      lds[(4*k + 3)*LDP + dc] = v3;
    }
    __syncthreads();
  }
}

__device__ inline void idwt_all(float* lds, int tid){
  idwt2_stage<1>(lds, tid);   idwt2_stage<4>(lds, tid);  idwt2_stage<16>(lds, tid);
  idwt2_stage<64>(lds, tid);  idwt2_stage<256>(lds, tid);
}

template<int N>
__device__ inline void dwt2_stage(float* lds, int tid){
  constexpr int ITEMS = N * DT;
  if constexpr (ITEMS >= TTH) {
    constexpr int PER = ITEMS / TTH;
    float va[PER], vd2[PER], vd1a[PER], vd1b[PER];
#pragma unroll
    for (int r = 0; r < PER; ++r){
      int idx = tid + r*TTH; int k = idx >> 4, dc = idx & 15;
      float x0 = lds[(4*k + 0)*LDP + dc];
      float x1 = lds[(4*k + 1)*LDP + dc];
      float x2 = lds[(4*k + 2)*LDP + dc];
      float x3 = lds[(4*k + 3)*LDP + dc];
      float a0 = (x0 + x1) * INVS, a1 = (x2 + x3) * INVS;
      vd1a[r] = (x0 - x1) * INVS; vd1b[r] = (x2 - x3) * INVS;
      va[r]  = (a0 + a1) * INVS;  vd2[r]  = (a0 - a1) * INVS;
    }
    __syncthreads();
#pragma unroll
    for (int r = 0; r < PER; ++r){
      int idx = tid + r*TTH; int k = idx >> 4, dc = idx & 15;
      lds[k*LDP + dc]                 = va[r];
      lds[(N + k)*LDP + dc]           = vd2[r];
      lds[(2*N + 2*k)*LDP + dc]       = vd1a[r];
      lds[(2*N + 2*k + 1)*LDP + dc]   = vd1b[r];
    }
    __syncthreads();
  } else {
    float va = 0.f, vd2 = 0.f, vd1a = 0.f, vd1b = 0.f;
    int k = tid >> 4, dc = tid & 15;
    bool act = tid < ITEMS;
    if (act){
      float x0 = lds[(4*k + 0)*LDP + dc];
      float x1 = lds[(4*k + 1)*LDP + dc];
      float x2 = lds[(4*k + 2)*LDP + dc];
      float x3 = lds[(4*k + 3)*LDP + dc];
      float a0 = (x0 + x1) * INVS, a1 = (x2 + x3) * INVS;
      vd1a = (x0 - x1) * INVS; vd1b = (x2 - x3) * INVS;
      va  = (a0 + a1) * INVS;  vd2  = (a0 - a1) * INVS;
    }
    __syncthreads();
    if (act){
      lds[k*LDP + dc]                 = va;
      lds[(N + k)*LDP + dc]           = vd2;
      lds[(2*N + 2*k)*LDP + dc]       = vd1a;
      lds[(2*N + 2*k + 1)*LDP + dc]   = vd1b;
    }
    __syncthreads();
  }
}

__device__ inline void dwt_all(float* lds, int tid){
  dwt2_stage<256>(lds, tid); dwt2_stage<64>(lds, tid); dwt2_stage<16>(lds, tid);
  dwt2_stage<4>(lds, tid);   dwt2_stage<1>(lds, tid);
}

// ---------------- kernel A: S = bf16(IDWT(w*rho))  (no c store) ----------------
__global__ __launch_bounds__(TTH, 4) void k_idwt_first(const float* __restrict__ rho,
                                                       const float* __restrict__ w,
                                                       unsigned short* __restrict__ S){
  __shared__ float lds[NT * LDP];
  int tid = threadIdx.x;
  int b = blockIdx.y;
  int d0 = blockIdx.x * DT;
  size_t base = ((size_t)b * NT) * ND;
  // stage ALL global loads first (16 independent loads in flight)
  float4 rv[8], wv[8];
#pragma unroll
  for (int r = 0; r < 8; ++r){
    int q = tid + r*TTH; int t = q >> 2, qq = q & 3;
    rv[r] = *(const float4*)(rho + base + (size_t)t*ND + d0 + qq*4);
  }
#pragma unroll
  for (int r = 0; r < 8; ++r){
    int q = tid + r*TTH; int t = q >> 2, qq = q & 3;
    wv[r] = *(const float4*)(w + (size_t)t*ND + d0 + qq*4);
  }
#pragma unroll
  for (int r = 0; r < 8; ++r){
    int q = tid + r*TTH; int t = q >> 2, qq = q & 3;
    float4 cv; cv.x = rv[r].x*wv[r].x; cv.y = rv[r].y*wv[r].y;
    cv.z = rv[r].z*wv[r].z; cv.w = rv[r].w*wv[r].w;
    *(float4*)(&lds[t*LDP + qq*4]) = cv;
  }
  __syncthreads();
  idwt_all(lds, tid);
#pragma unroll
  for (int r = 0; r < 8; ++r){
    int q = tid + r*TTH; int t = q >> 2, qq = q & 3;
    size_t g = base + (size_t)t*ND + d0 + qq*4;
    float4 v = *(float4*)(&lds[t*LDP + qq*4]);
    ushort4 o; o.x = f2bf(v.x); o.y = f2bf(v.y); o.z = f2bf(v.z); o.w = f2bf(v.w);
    *(ushort4*)(S + g) = o;
  }
}

// ---------------- kernel C: DWT(Y) -> c' = blend(w*rho, .) (store) -> IDWT -> S ----------------
__global__ __launch_bounds__(TTH, 4) void k_dwt_update_idwt(const unsigned short* __restrict__ Y,
                                                            const float* __restrict__ rho,
                                                            const float* __restrict__ w,
                                                            float* __restrict__ c,
                                                            unsigned short* __restrict__ S){
  __shared__ float lds[NT * LDP];
  int tid = threadIdx.x;
  int b = blockIdx.y;
  int d0 = blockIdx.x * DT;
  size_t base = ((size_t)b * NT) * ND;
  // stage Y loads + issue blend operands (rho,w) — all in flight before any use
  ushort4 yv[8];
#pragma unroll
  for (int r = 0; r < 8; ++r){
    int q = tid + r*TTH; int t = q >> 2, qq = q & 3;
    yv[r] = *(const ushort4*)(Y + base + (size_t)t*ND + d0 + qq*4);
  }
  float4 rv[8], wv[8];
#pragma unroll
  for (int r = 0; r < 8; ++r){
    int q = tid + r*TTH; int t = q >> 2, qq = q & 3;
    rv[r] = *(const float4*)(rho + base + (size_t)t*ND + d0 + qq*4);
  }
#pragma unroll
  for (int r = 0; r < 8; ++r){
    int q = tid + r*TTH; int t = q >> 2, qq = q & 3;
    wv[r] = *(const float4*)(w + (size_t)t*ND + d0 + qq*4);
  }
#pragma unroll
  for (int r = 0; r < 8; ++r){
    int q = tid + r*TTH; int t = q >> 2, qq = q & 3;
    lds[t*LDP + qq*4 + 0] = bf2f(yv[r].x);
    lds[t*LDP + qq*4 + 1] = bf2f(yv[r].y);
    lds[t*LDP + qq*4 + 2] = bf2f(yv[r].z);
    lds[t*LDP + qq*4 + 3] = bf2f(yv[r].w);
  }
  __syncthreads();
  dwt_all(lds, tid);
#pragma unroll
  for (int r = 0; r < 8; ++r){
    int q = tid + r*TTH; int t = q >> 2, qq = q & 3;
    size_t g = base + (size_t)t*ND + d0 + qq*4;
    float4 x = *(float4*)(&lds[t*LDP + qq*4]);
    float4 nc;
    float c0 = rv[r].x*wv[r].x, c1 = rv[r].y*wv[r].y, c2 = rv[r].z*wv[r].z, c3 = rv[r].w*wv[r].w;
    nc.x = c0 - ETA*(c0 - x.x);
    nc.y = c1 - ETA*(c1 - x.y);
    nc.z = c2 - ETA*(c2 - x.z);
    nc.w = c3 - ETA*(c3 - x.w);
    *(float4*)(c + g) = nc;
    *(float4*)(&lds[t*LDP + qq*4]) = nc;
  }
  __syncthreads();
  idwt_all(lds, tid);
#pragma unroll
  for (int r = 0; r < 8; ++r){
    int q = tid + r*TTH; int t = q >> 2, qq = q & 3;
    size_t g = base + (size_t)t*ND + d0 + qq*4;
    float4 v = *(float4*)(&lds[t*LDP + qq*4]);
    ushort4 o; o.x = f2bf(v.x); o.y = f2bf(v.y); o.z = f2bf(v.z); o.w = f2bf(v.w);
    *(ushort4*)(S + g) = o;
  }
}

// ---------------- kernel E: DWT(Y) -> out = blend(c', .)/w ----------------
__global__ __launch_bounds__(TTH, 4) void k_dwt_final(const unsigned short* __restrict__ Y,
                                                      float* __restrict__ c,
                                                      const float* __restrict__ w){
  __shared__ float lds[NT * LDP];
  int tid = threadIdx.x;
  int b = blockIdx.y;
  int d0 = blockIdx.x * DT;
  size_t base = ((size_t)b * NT) * ND;
  ushort4 yv[8];
#pragma unroll
  for (int r = 0; r < 8; ++r){
    int q = tid + r*TTH; int t = q >> 2, qq = q & 3;
    yv[r] = *(const ushort4*)(Y + base + (size_t)t*ND + d0 + qq*4);
  }
  float4 cv[8], wv[8];
#pragma unroll
  for (int r = 0; r < 8; ++r){
    int q = tid + r*TTH; int t = q >> 2, qq = q & 3;
    cv[r] = *(const float4*)(c + base + (size_t)t*ND + d0 + qq*4);
  }
#pragma unroll
  for (int r = 0; r < 8; ++r){
    int q = tid + r*TTH; int t = q >> 2, qq = q & 3;
    wv[r] = *(const float4*)(w + (size_t)t*ND + d0 + qq*4);
  }
#pragma unroll
  for (int r = 0; r < 8; ++r){
    int q = tid + r*TTH; int t = q >> 2, qq = q & 3;
    lds[t*LDP + qq*4 + 0] = bf2f(yv[r].x);
    lds[t*LDP + qq*4 + 1] = bf2f(yv[r].y);
    lds[t*LDP + qq*4 + 2] = bf2f(yv[r].z);
    lds[t*LDP + qq*4 + 3] = bf2f(yv[r].w);
  }
  __syncthreads();
  dwt_all(lds, tid);
#pragma unroll
  for (int r = 0; r < 8; ++r){
    int q = tid + r*TTH; int t = q >> 2, qq = q & 3;
    size_t g = base + (size_t)t*ND + d0 + qq*4;
    float4 x = *(float4*)(&lds[t*LDP + qq*4]);
    float4 ov;
    ov.x = (cv[r].x - ETA*(cv[r].x - x.x)) / wv[r].x;
    ov.y = (cv[r].y - ETA*(cv[r].y - x.y)) / wv[r].y;
    ov.z = (cv[r].z - ETA*(cv[r].z - x.z)) / wv[r].z;
    ov.w = (cv[r].w - ETA*(cv[r].w - x.w)) / wv[r].w;
    *(float4*)(c + g) = ov;
  }
}

// ---------------- per-band GEMM, register-held B panel, TM=2 tiles/block ----------------
__global__ __launch_bounds__(256, 2) void k_band_gemm(const unsigned short* __restrict__ S,
                                                      const unsigned short* __restrict__ Wt,
                                                      const float* __restrict__ bias,
                                                      unsigned short* __restrict__ Y){
  int bx = blockIdx.x;  // 0..591
  int wv = threadIdx.x >> 6, lane = threadIdx.x & 63;
  int row = lane & 15, kg = lane >> 4;
  int band, jbase; bool masked = false;
  if      (bx <  16){ band =  6; jbase = bx*2; }
  else if (bx <  48){ band =  7; jbase = (bx-16)*2; }
  else if (bx < 112){ band =  8; jbase = (bx-48)*2; }
  else if (bx < 240){ band =  9; jbase = (bx-112)*2; }
  else if (bx < 496){ band = 10; jbase = (bx-240)*2; }
  else { masked = true; int mb = bx-496; band = mb>>4; jbase = (mb&15)*2; }

  int n0 = wv * 64;
  const unsigned short* Wb = Wt + (size_t)band * 65536;

  bf16x8 breg[8][4];
#pragma unroll
  for (int kk = 0; kk < 8; ++kk)
#pragma unroll
    for (int ni = 0; ni < 4; ++ni)
      breg[kk][ni] = *(const bf16x8*)(Wb + (size_t)(n0 + 16*ni + row)*256 + kk*32 + kg*8);

  float bv[4];
#pragma unroll
  for (int ni = 0; ni < 4; ++ni) bv[ni] = bias[band*256 + n0 + 16*ni + row];

  int lo = 0, hi = 0;
  if (masked){
    lo = (band == 0) ? 0 : (1 << (band - 1));
    hi = (band == 0) ? 1 : (1 << band);
  }
  int shift = masked ? 0 : (band - 6);
  int tstart = masked ? 0 : (32 << shift);

  for (int m = 0; m < 2; ++m){
    int j = jbase + m;
    int bb, t0;
    if (masked){ bb = j; t0 = 0; }
    else { bb = j >> shift; t0 = tstart + (j & ((1 << shift) - 1)) * 32; }

    f32x4 acc[2][4];
#pragma unroll
    for (int mi = 0; mi < 2; ++mi)
#pragma unroll
      for (int ni = 0; ni < 4; ++ni) acc[mi][ni] = (f32x4){0.f, 0.f, 0.f, 0.f};

    size_t arow0 = ((size_t)bb * NT + t0 + row) * ND;
#pragma unroll
    for (int kk = 0; kk < 8; ++kk){
      int k = kk*32 + kg*8;
      bf16x8 a0 = *(const bf16x8*)(S + arow0 + k);
      bf16x8 a1 = *(const bf16x8*)(S + arow0 + 16*ND + k);
#pragma unroll
      for (int ni = 0; ni < 4; ++ni){
        acc[0][ni] = __builtin_amdgcn_mfma_f32_16x16x32_bf16(a0, breg[kk][ni], acc[0][ni], 0, 0, 0);
        acc[1][ni] = __builtin_amdgcn_mfma_f32_16x16x32_bf16(a1, breg[kk][ni], acc[1][ni], 0, 0, 0);
      }
    }
#pragma unroll
    for (int ni = 0; ni < 4; ++ni){
#pragma unroll
      for (int mi = 0; mi < 2; ++mi){
#pragma unroll
        for (int jj = 0; jj < 4; ++jj){
          int t = t0 + 16*mi + kg*4 + jj;   // C/D: row=(lane>>4)*4+reg, col=lane&15
          if (!masked || (t >= lo && t < hi)){
            Y[((size_t)bb*NT + t)*ND + n0 + 16*ni + row] = f2bf(acc[mi][ni][jj] + bv[ni]);
          }
        }
      }
    }
  }
}

// ---------------- Wt[band][e][d] = bf16(W[band][d][e]) ----------------
__global__ __launch_bounds__(256) void k_wprep(const float* __restrict__ W,
                                               unsigned short* __restrict__ Wt){
  __shared__ float tbuf[32][33];
  int band = blockIdx.y;
  int tile = blockIdx.x;             // 0..63 -> 8x8 grid of 32x32 tiles
  int td0 = (tile >> 3) * 32, te0 = (tile & 7) * 32;
  int tx = threadIdx.x & 31, ty = threadIdx.x >> 5;
#pragma unroll
  for (int i = 0; i < 4; ++i){
    tbuf[ty*4 + i][tx] = W[(size_t)band*65536 + (size_t)(td0 + ty*4 + i)*256 + te0 + tx];
  }
  __syncthreads();
#pragma unroll
  for (int i = 0; i < 4; ++i){
    Wt[(size_t)band*65536 + (size_t)(te0 + ty*4 + i)*256 + td0 + tx] = f2bf(tbuf[tx][ty*4 + i]);
  }
}

extern "C" void kernel_launch(void* const* d_in, const int* in_sizes, int n_in,
                              void* d_out, int out_size, void* d_ws, size_t ws_size,
                              hipStream_t stream){
  const float* rho  = (const float*)d_in[0];
  const float* w    = (const float*)d_in[1];
  const float* W    = (const float*)d_in[2];
  const float* bias = (const float*)d_in[3];

  float* c = (float*)d_out;                                   // coeff state lives in d_out
  unsigned short* S  = (unsigned short*)d_ws;                 // 16 MB bf16 signal
  unsigned short* Y  = S + (size_t)NB * NT * ND;              // 16 MB bf16 predicted signal
  unsigned short* Wt = Y + (size_t)NB * NT * ND;              // 1.4 MB bf16 transposed weights

  k_wprep<<<dim3(64, 11), 256, 0, stream>>>(W, Wt);
  k_idwt_first<<<dim3(ND/DT, NB), TTH, 0, stream>>>(rho, w, S);
  k_band_gemm<<<592, 256, 0, stream>>>(S, Wt, bias, Y);
  k_dwt_update_idwt<<<dim3(ND/DT, NB), TTH, 0, stream>>>(Y, rho, w, c, S);
  k_band_gemm<<<592, 256, 0, stream>>>(S, Wt, bias, Y);
  k_dwt_final<<<dim3(ND/DT, NB), TTH, 0, stream>>>(Y, c, w);
}